// Round 1
// 561.475 us; speedup vs baseline: 1.0563x; 1.0563x over previous
//
#include <hip/hip_runtime.h>
#include <cstdint>

#define MDIM 4096
#define NDIM 9216
#define KDIM 3072
#define KP   3136   // 3072 + 32 lora + 32 zero pad = 98 tiles of 32
#define NKT2 97     // GEMM covers 97 K-tiles of 32 (3104 cols); zero tail tile skipped

#define QB 4096            // quant blocks (one row each)
#define WB 13824           // weight-dequant blocks
#define PB 2304            // B-pad blocks (9216*64/256)

typedef unsigned int u32;
typedef unsigned short u16;
typedef float f32x4 __attribute__((ext_vector_type(4)));
typedef __bf16 bf16x8 __attribute__((ext_vector_type(8)));

__device__ __forceinline__ u16 f2bf(float f) {
  u32 u = __float_as_uint(f);
  u32 r = u + 0x7fffu + ((u >> 16) & 1u);   // round-to-nearest-even
  return (u16)(r >> 16);
}

__device__ __forceinline__ float frcp(float f) { return __builtin_amdgcn_rcpf(f); }

__device__ __forceinline__ void gld_lds16(const void* g, void* l) {
  __builtin_amdgcn_global_load_lds((__attribute__((address_space(1))) void*)g,
                                   (__attribute__((address_space(3))) void*)l,
                                   16, 0, 0);
}

// ---------------- kernel 1: fused prep (unchanged) ----------------
__global__ __launch_bounds__(256) void k_prep(const float* __restrict__ x, const u32* __restrict__ qw,
                        const float* __restrict__ wsc, const float* __restrict__ lora_down,
                        const float* __restrict__ lora_up, const float* __restrict__ smooth,
                        u16* __restrict__ Aex, u16* __restrict__ Bex) {
  __shared__ float xs_s[KDIM];        // 12 KB
  __shared__ float part[64 * 32];     // 8 KB  [chunk][rank]
  const int tid = threadIdx.x;
  int bid = blockIdx.x;

  if (bid >= QB) {
    bid -= QB;
    if (bid >= WB) {
      int idx = (bid - WB) * 256 + tid;        // < 9216*64
      int n = idx >> 6, c = idx & 63;
      u16 v = 0;
      if (c < 32) v = f2bf(lora_up[n * 32 + c]);
      Bex[(size_t)n * KP + 3072 + c] = v;
      return;
    }
    // ---- weight dequant path ----
    __shared__ int s_viol;
    u32 probe = qw[tid];
    bool ok = (probe >> 8) == ((probe & 0x80u) ? 0xffffffu : 0u);
    if (tid == 0) s_viol = 0;
    __syncthreads();
    if (!ok) atomicOr(&s_viol, 1);
    __syncthreads();
    const int f = (s_viol == 0);

    int idx = bid * 256 + tid;   // < 9216*384
    int n = idx / 384;
    int j = idx - n * 384;
    int k0 = j * 8;
    u32 w;
    if (f) {
      uint4 q4 = ((const uint4*)qw)[idx];
      w = (q4.x & 0xffu) | ((q4.y & 0xffu) << 8) | ((q4.z & 0xffu) << 16) | ((q4.w & 0xffu) << 24);
    } else {
      w = qw[idx];
    }
    float ws = wsc[(k0 >> 6) * NDIM + n];
    u32 ow[4];
    #pragma unroll
    for (int b = 0; b < 4; ++b) {
      int by = (int)((w >> (8 * b)) & 0xffu);
      int lo = (by << 28) >> 28;
      int hi = (by << 24) >> 28;
      ow[b] = (u32)f2bf((float)lo * ws) | ((u32)f2bf((float)hi * ws) << 16);
    }
    *(uint4*)(Bex + (size_t)n * KP + k0) = make_uint4(ow[0], ow[1], ow[2], ow[3]);
    return;
  }

  // ---- quant path: one row m = bid ----
  const int m = bid;
  const int sub = tid & 15;
  const float* xr = x + (size_t)m * KDIM;
  u16* arow = Aex + (size_t)m * KP;

  #pragma unroll
  for (int p = 0; p < 3; ++p) {
    int g = p * 16 + (tid >> 4);
    int k0 = g * 64 + sub * 4;
    float4 xv = *(const float4*)(xr + k0);
    float4 sv = *(const float4*)(smooth + k0);
    float a0 = xv.x * frcp(sv.x), a1 = xv.y * frcp(sv.y);
    float a2 = xv.z * frcp(sv.z), a3 = xv.w * frcp(sv.w);
    xs_s[k0+0] = a0; xs_s[k0+1] = a1; xs_s[k0+2] = a2; xs_s[k0+3] = a3;
    float am = fmaxf(fmaxf(fabsf(a0), fabsf(a1)), fmaxf(fabsf(a2), fabsf(a3)));
    am = fmaxf(am, __shfl_xor(am, 8, 16));
    am = fmaxf(am, __shfl_xor(am, 4, 16));
    am = fmaxf(am, __shfl_xor(am, 2, 16));
    am = fmaxf(am, __shfl_xor(am, 1, 16));
    float asc = fmaxf(am * (1.0f / 7.0f), 1e-8f);
    float iasc = frcp(asc);
    float q0 = fminf(7.f, fmaxf(-8.f, rintf(a0 * iasc)));
    float q1 = fminf(7.f, fmaxf(-8.f, rintf(a1 * iasc)));
    float q2 = fminf(7.f, fmaxf(-8.f, rintf(a2 * iasc)));
    float q3 = fminf(7.f, fmaxf(-8.f, rintf(a3 * iasc)));
    float d0 = q0 * asc, d1 = q1 * asc, d2 = q2 * asc, d3 = q3 * asc;
    u32 lo = (u32)f2bf(d0) | ((u32)f2bf(d1) << 16);
    u32 hi = (u32)f2bf(d2) | ((u32)f2bf(d3) << 16);
    *(uint2*)(arow + k0) = make_uint2(lo, hi);
  }
  if (tid < 32) arow[3104 + tid] = 0;   // zero pad tail
  __syncthreads();

  {
    const int c  = tid >> 2;
    const int r8 = (tid & 3) * 8;
    float a[8] = {0.f, 0.f, 0.f, 0.f, 0.f, 0.f, 0.f, 0.f};
    const float* lp = lora_down + (size_t)c * 32 + r8;
    #pragma unroll 4
    for (int i = 0; i < 48; ++i) {
      float xv = xs_s[i * 64 + c];
      float4 l0 = *(const float4*)(lp);
      float4 l1 = *(const float4*)(lp + 4);
      a[0] = fmaf(xv, l0.x, a[0]); a[1] = fmaf(xv, l0.y, a[1]);
      a[2] = fmaf(xv, l0.z, a[2]); a[3] = fmaf(xv, l0.w, a[3]);
      a[4] = fmaf(xv, l1.x, a[4]); a[5] = fmaf(xv, l1.y, a[5]);
      a[6] = fmaf(xv, l1.z, a[6]); a[7] = fmaf(xv, l1.w, a[7]);
      lp += 64 * 32;
    }
    __syncthreads();
    *(float4*)(&part[c * 32 + r8])     = make_float4(a[0], a[1], a[2], a[3]);
    *(float4*)(&part[c * 32 + r8 + 4]) = make_float4(a[4], a[5], a[6], a[7]);
  }
  __syncthreads();
  if (tid < 32) {
    float s = 0.f;
    #pragma unroll 8
    for (int cc = 0; cc < 64; ++cc) s += part[cc * 32 + tid];
    arow[3072 + tid] = f2bf(s);   // LORA_SCALE = 1.0
  }
}

// ---------------- kernel 2: 256x256 deep-pipelined MFMA GEMM + fused epilogue ----------------
// 512 threads = 8 waves (2M x 4N), wave tile 128x64 (acc 8x4 of 16x16).
// BK=32, 4-slot LDS ring (4 x 32KB = 128KB dynamic LDS), prefetch distance 3 K-tiles,
// counted s_waitcnt vmcnt(8) at K-tile boundaries (never drains to 0 in steady state).
// LDS layout per slot: A then B, each 256 logical rows x 32 cols bf16 packed as
// [128 physical rows][8 chunks of 16B], chunk swizzle c' = c ^ (pr&7) (2-way worst = free).
// Race-freedom: slot (kt+3)&3 == (kt-1)&3 is only written after the barrier that closes
// kt-1's reads (reads drained by lgkmcnt(0) before kt-1's MFMAs, which precede that barrier).
__global__ __launch_bounds__(512) void k_gemm(const u16* __restrict__ A, const u16* __restrict__ B,
                                              const float* __restrict__ bias, const float* __restrict__ norm_q,
                                              const float* __restrict__ norm_k, const float* __restrict__ rot,
                                              float* __restrict__ out) {
  extern __shared__ u16 lds[];   // 4 slots * 16384 u16 = 128 KB
  const int tid  = threadIdx.x;
  const int lane = tid & 63;
  const int wave = tid >> 6;
  const int m0 = blockIdx.y * 256;
  const int n0 = blockIdx.x * 256;
  const int wm = (wave >> 2) * 128;
  const int wn = (wave & 3) * 64;
  const int lr = lane & 15;
  const int lq = lane >> 4;

  // ---- staging addresses: 2 A chunks + 2 B chunks per thread per K-tile ----
  // LDS chunk p (linear, wave-uniform-base + lane*16 as required by global_load_lds);
  // global source is pre-inverse-swizzled so the read side can use c ^ (pr&7).
  const u16 *pA0, *pA1, *pB0, *pB1;
  int la0, la1, lb0, lb1;
  {
    auto mk = [&](int p, const u16* base, int nb) -> const u16* {
      int pr = p >> 3, cs = p & 7;
      int c  = cs ^ (pr & 7);
      int r  = pr * 2 + (c >> 2);    // logical row (row-paired layout)
      int kc = c & 3;                // 8-col chunk within BK=32
      return base + (size_t)(nb + r) * KP + kc * 8;
    };
    int p0 = tid, p1 = 512 + tid;
    pA0 = mk(p0, A, m0); pA1 = mk(p1, A, m0);
    pB0 = mk(p0, B, n0); pB1 = mk(p1, B, n0);
    la0 = p0 * 8;        la1 = p1 * 8;
    lb0 = 8192 + p0 * 8; lb1 = 8192 + p1 * 8;
  }

  // ---- fragment LDS offsets (u16 units within a slot) ----
  int aoff[8], boff[4];
  #pragma unroll
  for (int t = 0; t < 8; ++t) {
    int ra = wm + t * 16 + lr;
    int pr = ra >> 1, c = (ra & 1) * 4 + lq;
    aoff[t] = pr * 64 + ((c ^ (pr & 7)) * 8);
  }
  #pragma unroll
  for (int t = 0; t < 4; ++t) {
    int rb = wn + t * 16 + lr;
    int pr = rb >> 1, c = (rb & 1) * 4 + lq;
    boff[t] = 8192 + pr * 64 + ((c ^ (pr & 7)) * 8);
  }

  f32x4 acc[8][4] = {};

  // ---- prologue: stage K-tiles 0,1,2 into slots 0,1,2 (12 loads/wave) ----
  #pragma unroll
  for (int s = 0; s < 3; ++s) {
    u16* sl = lds + (s << 14);
    gld_lds16(pA0, sl + la0); gld_lds16(pA1, sl + la1);
    gld_lds16(pB0, sl + lb0); gld_lds16(pB1, sl + lb1);
    pA0 += 32; pA1 += 32; pB0 += 32; pB1 += 32;
  }
  asm volatile("s_waitcnt vmcnt(8)" ::: "memory");   // K-tile 0 resident; 1,2 in flight
  __builtin_amdgcn_s_barrier();

  #pragma unroll 1
  for (int kt = 0; kt < NKT2; ++kt) {
    const u16* sA_ = lds + ((kt & 3) << 14);
    u16* stl = lds + (((kt + 3) & 3) << 14);
    const bool st = (kt < NKT2 - 3);
    bf16x8 af[4], bf[4];

    // ---------- phase 0: stage A of kt+3 | read frags | MFMA ti 0..3 ----------
    if (st) { gld_lds16(pA0, stl + la0); gld_lds16(pA1, stl + la1); }
    #pragma unroll
    for (int t = 0; t < 4; ++t) af[t] = *(const bf16x8*)&sA_[aoff[t]];
    #pragma unroll
    for (int t = 0; t < 4; ++t) bf[t] = *(const bf16x8*)&sA_[boff[t]];
    __builtin_amdgcn_s_barrier();
    asm volatile("s_waitcnt lgkmcnt(0)" ::: "memory");
    __builtin_amdgcn_sched_barrier(0);
    __builtin_amdgcn_s_setprio(1);
    #pragma unroll
    for (int ti = 0; ti < 4; ++ti)
      #pragma unroll
      for (int tj = 0; tj < 4; ++tj)
        acc[ti][tj] = __builtin_amdgcn_mfma_f32_16x16x32_bf16(af[ti], bf[tj], acc[ti][tj], 0, 0, 0);
    __builtin_amdgcn_s_setprio(0);
    __builtin_amdgcn_sched_barrier(0);
    __builtin_amdgcn_s_barrier();

    // ---------- phase 1: stage B of kt+3 | read A frags ti 4..7 | MFMA ----------
    if (st) { gld_lds16(pB0, stl + lb0); gld_lds16(pB1, stl + lb1);
              pA0 += 32; pA1 += 32; pB0 += 32; pB1 += 32; }
    #pragma unroll
    for (int t = 0; t < 4; ++t) af[t] = *(const bf16x8*)&sA_[aoff[4 + t]];
    __builtin_amdgcn_s_barrier();
    asm volatile("s_waitcnt lgkmcnt(0)" ::: "memory");
    __builtin_amdgcn_sched_barrier(0);
    __builtin_amdgcn_s_setprio(1);
    #pragma unroll
    for (int ti = 0; ti < 4; ++ti)
      #pragma unroll
      for (int tj = 0; tj < 4; ++tj)
        acc[4 + ti][tj] = __builtin_amdgcn_mfma_f32_16x16x32_bf16(af[ti], bf[tj], acc[4 + ti][tj], 0, 0, 0);
    __builtin_amdgcn_s_setprio(0);
    __builtin_amdgcn_sched_barrier(0);
    // boundary: retire only kt+1's 4 loads; keep kt+2/kt+3 in flight
    if (st) asm volatile("s_waitcnt vmcnt(8)" ::: "memory");
    else    asm volatile("s_waitcnt vmcnt(0)" ::: "memory");
    __builtin_amdgcn_s_barrier();
  }

  // ---- epilogue.  C/D layout: col = lane&15, row = (lane>>4)*4 + reg ----
  // block covers 2 heads (256 cols); sel uniform per block (256 | 3072)
  const int sel = (blockIdx.x >= 24) ? 2 : (blockIdx.x >= 12 ? 1 : 0);

  float bv[4];
  #pragma unroll
  for (int tj = 0; tj < 4; ++tj) bv[tj] = bias[n0 + wn + tj * 16 + lr];
  #pragma unroll
  for (int ti = 0; ti < 8; ++ti)
    #pragma unroll
    for (int tj = 0; tj < 4; ++tj)
      #pragma unroll
      for (int rg = 0; rg < 4; ++rg)
        acc[ti][tj][rg] += bv[tj];

  if (sel == 2) {
    #pragma unroll
    for (int tj = 0; tj < 4; ++tj) {
      int n = n0 + wn + tj * 16 + lr;
      #pragma unroll
      for (int ti = 0; ti < 8; ++ti) {
        int mr = m0 + wm + ti * 16 + lq * 4;
        #pragma unroll
        for (int rg = 0; rg < 4; ++rg)
          out[(size_t)(mr + rg) * NDIM + n] = acc[ti][tj][rg];
      }
    }
    return;
  }

  // RMSNorm: per-row sum of squares over each head's 128 cols.
  // ssq[(wn>>6)][row 0..255] — head h total = ssq[2h][r] + ssq[2h+1][r]. LDS is dead.
  float* ssq = (float*)lds;
  #pragma unroll
  for (int ti = 0; ti < 8; ++ti) {
    float pr4[4];
    #pragma unroll
    for (int rg = 0; rg < 4; ++rg) {
      float s = 0.f;
      #pragma unroll
      for (int tj = 0; tj < 4; ++tj) s += acc[ti][tj][rg] * acc[ti][tj][rg];
      pr4[rg] = s;
    }
    #pragma unroll
    for (int off = 1; off < 16; off <<= 1)
      #pragma unroll
      for (int rg = 0; rg < 4; ++rg) pr4[rg] += __shfl_xor(pr4[rg], off);
    #pragma unroll
    for (int rg = 0; rg < 4; ++rg)
      if (lr == (ti & 3) * 4 + rg)
        ssq[(wn >> 6) * 256 + wm + ti * 16 + lq * 4 + rg] = pr4[rg];
  }
  __syncthreads();

  const float* nrm = sel ? norm_k : norm_q;
  float gm[4];
  #pragma unroll
  for (int tj = 0; tj < 4; ++tj) gm[tj] = nrm[(wn & 64) + tj * 16 + lr];
  const float2* rot2 = (const float2*)rot;
  const float sgn = (lr & 1) ? 1.0f : -1.0f;
  const int hb = (wn >> 7) * 512;

  #pragma unroll
  for (int ti = 0; ti < 8; ++ti) {
    #pragma unroll
    for (int rg = 0; rg < 4; ++rg) {
      int row = wm + ti * 16 + lq * 4 + rg;
      float tot = ssq[hb + row] + ssq[hb + 256 + row];
      float rs = rsqrtf(tot * (1.0f / 128.0f) + 1e-6f);
      int m = m0 + row;
      #pragma unroll
      for (int tj = 0; tj < 4; ++tj) {
        int nl = (wn & 64) + tj * 16 + lr;          // head-local col
        float v = acc[ti][tj][rg] * rs * gm[tj];
        float p = __shfl_xor(v, 1);                 // rope partner (same row, col^1)
        float2 cs = rot2[(size_t)m * 64 + (nl >> 1)];
        out[(size_t)m * NDIM + n0 + wn + tj * 16 + lr] = v * cs.x + sgn * (p * cs.y);
      }
    }
  }
}

extern "C" void kernel_launch(void* const* d_in, const int* in_sizes, int n_in,
                              void* d_out, int out_size, void* d_ws, size_t ws_size,
                              hipStream_t stream) {
  const float* x         = (const float*)d_in[0];
  const u32*   qweight   = (const u32*)d_in[1];
  const float* wscales   = (const float*)d_in[2];
  const float* bias      = (const float*)d_in[3];
  const float* lora_down = (const float*)d_in[4];
  const float* lora_up   = (const float*)d_in[5];
  const float* smooth    = (const float*)d_in[6];
  const float* norm_q    = (const float*)d_in[7];
  const float* norm_k    = (const float*)d_in[8];
  const float* rot       = (const float*)d_in[9];
  float* out = (float*)d_out;

  u16* Aex = (u16*)d_ws;                               // 4096*3136 bf16
  u16* Bex = Aex + (size_t)MDIM * KP;                  // 9216*3136 bf16

  static bool attr_set = false;
  if (!attr_set) {
    hipFuncSetAttribute(reinterpret_cast<const void*>(k_gemm),
                        hipFuncAttributeMaxDynamicSharedMemorySize, 131072);
    attr_set = true;
  }

  k_prep<<<QB + WB + PB, 256, 0, stream>>>(x, qweight, wscales, lora_down, lora_up, smooth, Aex, Bex);
  k_gemm<<<dim3(NDIM / 256, MDIM / 256), 512, 131072, stream>>>(Aex, Bex, bias, norm_q, norm_k, rot, out);
}

// Round 3
// 531.898 us; speedup vs baseline: 1.1151x; 1.0556x over previous
//
#include <hip/hip_runtime.h>
#include <cstdint>

#define MDIM 4096
#define NDIM 9216
#define KDIM 3072
#define KP   3136   // 3072 + 32 lora + 32 zero pad = 98 tiles of 32
#define NKT2 97     // GEMM covers 97 K-tiles of 32 (3104 cols); zero tail tile skipped

#define QROWS 4
#define QB2 1024           // quant blocks (4 rows each)
#define WB 13824           // weight-dequant blocks
#define PB 2304            // B-pad blocks (9216*64/256)

typedef unsigned int u32;
typedef unsigned short u16;
typedef float f32x4 __attribute__((ext_vector_type(4)));
typedef __bf16 bf16x8 __attribute__((ext_vector_type(8)));

__device__ __forceinline__ u16 f2bf(float f) {
  u32 u = __float_as_uint(f);
  u32 r = u + 0x7fffu + ((u >> 16) & 1u);   // round-to-nearest-even
  return (u16)(r >> 16);
}

__device__ __forceinline__ float frcp(float f) { return __builtin_amdgcn_rcpf(f); }

__device__ __forceinline__ void gld_lds16(const void* g, void* l) {
  __builtin_amdgcn_global_load_lds((__attribute__((address_space(1))) void*)g,
                                   (__attribute__((address_space(3))) void*)l,
                                   16, 0, 0);
}

// ---------------- kernel 1a: activation smooth+quant+lora_act, 4 rows/block ----------------
// lora_down (384 KB) is read once per block instead of once per row: 4x less L2 traffic.
__global__ __launch_bounds__(256) void k_quant(const float* __restrict__ x,
                        const float* __restrict__ lora_down, const float* __restrict__ smooth,
                        u16* __restrict__ Aex) {
  __shared__ float xs_s[QROWS][KDIM];   // 48 KB
  __shared__ float part[64 * 32];       // 8 KB  [chunk][rank]
  const int tid = threadIdx.x;
  const int m0 = blockIdx.x * QROWS;
  const int sub = tid & 15;

  #pragma unroll
  for (int r = 0; r < QROWS; ++r) {
    const float* xr = x + (size_t)(m0 + r) * KDIM;
    u16* arow = Aex + (size_t)(m0 + r) * KP;
    #pragma unroll
    for (int p = 0; p < 3; ++p) {
      int g = p * 16 + (tid >> 4);
      int k0 = g * 64 + sub * 4;
      float4 xv = *(const float4*)(xr + k0);
      float4 sv = *(const float4*)(smooth + k0);
      float a0 = xv.x * frcp(sv.x), a1 = xv.y * frcp(sv.y);
      float a2 = xv.z * frcp(sv.z), a3 = xv.w * frcp(sv.w);
      xs_s[r][k0+0] = a0; xs_s[r][k0+1] = a1; xs_s[r][k0+2] = a2; xs_s[r][k0+3] = a3;
      float am = fmaxf(fmaxf(fabsf(a0), fabsf(a1)), fmaxf(fabsf(a2), fabsf(a3)));
      am = fmaxf(am, __shfl_xor(am, 8, 16));
      am = fmaxf(am, __shfl_xor(am, 4, 16));
      am = fmaxf(am, __shfl_xor(am, 2, 16));
      am = fmaxf(am, __shfl_xor(am, 1, 16));
      float asc = fmaxf(am * (1.0f / 7.0f), 1e-8f);
      float iasc = frcp(asc);
      float q0 = fminf(7.f, fmaxf(-8.f, rintf(a0 * iasc)));
      float q1 = fminf(7.f, fmaxf(-8.f, rintf(a1 * iasc)));
      float q2 = fminf(7.f, fmaxf(-8.f, rintf(a2 * iasc)));
      float q3 = fminf(7.f, fmaxf(-8.f, rintf(a3 * iasc)));
      float d0 = q0 * asc, d1 = q1 * asc, d2 = q2 * asc, d3 = q3 * asc;
      u32 lo = (u32)f2bf(d0) | ((u32)f2bf(d1) << 16);
      u32 hi = (u32)f2bf(d2) | ((u32)f2bf(d3) << 16);
      *(uint2*)(arow + k0) = make_uint2(lo, hi);
    }
    if (tid < 32) arow[3104 + tid] = 0;   // zero pad tail
  }
  __syncthreads();

  // lora_act[r_row][rk] = sum_k xs[r_row][k] * lora_down[k][rk]
  // thread = (chunk c = tid>>2 of 64, ranks r8..r8+7); k = i*64 + c
  const int c  = tid >> 2;
  const int r8 = (tid & 3) * 8;
  float a[QROWS][8] = {};
  const float* lp = lora_down + (size_t)c * 32 + r8;   // advance 64*32 floats per i
  #pragma unroll 2
  for (int i = 0; i < 48; ++i) {
    float4 l0 = *(const float4*)(lp);
    float4 l1 = *(const float4*)(lp + 4);
    #pragma unroll
    for (int r = 0; r < QROWS; ++r) {
      float xv = xs_s[r][i * 64 + c];
      a[r][0] = fmaf(xv, l0.x, a[r][0]); a[r][1] = fmaf(xv, l0.y, a[r][1]);
      a[r][2] = fmaf(xv, l0.z, a[r][2]); a[r][3] = fmaf(xv, l0.w, a[r][3]);
      a[r][4] = fmaf(xv, l1.x, a[r][4]); a[r][5] = fmaf(xv, l1.y, a[r][5]);
      a[r][6] = fmaf(xv, l1.z, a[r][6]); a[r][7] = fmaf(xv, l1.w, a[r][7]);
    }
    lp += 64 * 32;
  }
  #pragma unroll 1
  for (int r = 0; r < QROWS; ++r) {
    __syncthreads();
    *(float4*)(&part[c * 32 + r8])     = make_float4(a[r][0], a[r][1], a[r][2], a[r][3]);
    *(float4*)(&part[c * 32 + r8 + 4]) = make_float4(a[r][4], a[r][5], a[r][6], a[r][7]);
    __syncthreads();
    if (tid < 32) {
      float s = 0.f;
      #pragma unroll 8
      for (int cc = 0; cc < 64; ++cc) s += part[cc * 32 + tid];
      Aex[(size_t)(m0 + r) * KP + 3072 + tid] = f2bf(s);   // LORA_SCALE = 1.0
    }
  }
}

// ---------------- kernel 1b: int4 weight dequant + B lora/pad columns ----------------
__global__ __launch_bounds__(256) void k_wdq(const u32* __restrict__ qw,
                        const float* __restrict__ wsc, const float* __restrict__ lora_up,
                        u16* __restrict__ Bex) {
  const int tid = threadIdx.x;
  int bid = blockIdx.x;

  if (bid >= WB) {
    // ---- pad path: Bex[:, 3072:3136) = lora_up | 0 ----
    int idx = (bid - WB) * 256 + tid;        // < 9216*64
    int n = idx >> 6, c = idx & 63;
    u16 v = 0;
    if (c < 32) v = f2bf(lora_up[n * 32 + c]);
    Bex[(size_t)n * KP + 3072 + c] = v;
    return;
  }
  // ---- weight dequant path ----
  // per-block layout detect: int8 stored as sign-extended int32 (f=1) vs raw bytes (f=0)
  __shared__ int s_viol;
  u32 probe = qw[tid];
  bool ok = (probe >> 8) == ((probe & 0x80u) ? 0xffffffu : 0u);
  if (tid == 0) s_viol = 0;
  __syncthreads();
  if (!ok) atomicOr(&s_viol, 1);
  __syncthreads();
  const int f = (s_viol == 0);

  int idx = bid * 256 + tid;   // < 9216*384
  int n = idx / 384;
  int j = idx - n * 384;
  int k0 = j * 8;
  u32 w;
  if (f) {
    uint4 q4 = ((const uint4*)qw)[idx];      // 4 sign-extended int32s, coalesced 16B
    w = (q4.x & 0xffu) | ((q4.y & 0xffu) << 8) | ((q4.z & 0xffu) << 16) | ((q4.w & 0xffu) << 24);
  } else {
    w = qw[idx];
  }
  float ws = wsc[(k0 >> 6) * NDIM + n];
  u32 ow[4];
  #pragma unroll
  for (int b = 0; b < 4; ++b) {
    int by = (int)((w >> (8 * b)) & 0xffu);
    int lo = (by << 28) >> 28;   // low nibble (k even)
    int hi = (by << 24) >> 28;   // high nibble (k odd)
    ow[b] = (u32)f2bf((float)lo * ws) | ((u32)f2bf((float)hi * ws) << 16);
  }
  *(uint4*)(Bex + (size_t)n * KP + k0) = make_uint4(ow[0], ow[1], ow[2], ow[3]);
}

// ---------------- kernel 2: 256x256 MFMA GEMM, 1-barrier ring pipeline + fused epilogue ----------------
// 512 threads = 8 waves (2M x 4N), wave tile 128x64 (acc 8x4 of 16x16).
// BK=32, 4-slot LDS ring (128 KB dynamic), prefetch distance 3 K-tiles.
// ONE s_barrier + ONE counted vmcnt(8) per K-tile; no manual lgkmcnt (compiler emits
// fine-grained lgkm waits for ds_read->MFMA), no sched_barrier fences.
// Invariant: after barrier(j), stores of iters <= j-2 are retired (vmcnt 8 = newest
// 2 iters x 4 loads) -> slot j+1 fully resident when iter j+1 reads it.
// WAR safety: stores of iter kt hit slot kt+3 == kt-1 (mod 4); every wave's slot-(kt-1)
// ds_reads completed before its own MFMAs, which precede barrier(kt-1) < the stores.
// NOTE: raw s_barrier is NOT a compiler memory fence -> an empty asm "memory" clobber
// follows every barrier so ds_reads cannot be hoisted above it (other waves' staging
// of the slot is only guaranteed complete after the barrier).
__global__ __launch_bounds__(512) void k_gemm(const u16* __restrict__ A, const u16* __restrict__ B,
                                              const float* __restrict__ bias, const float* __restrict__ norm_q,
                                              const float* __restrict__ norm_k, const float* __restrict__ rot,
                                              float* __restrict__ out) {
  extern __shared__ u16 lds[];   // 4 slots * 16384 u16 = 128 KB
  const int tid  = threadIdx.x;
  const int lane = tid & 63;
  const int wave = tid >> 6;
  const int m0 = blockIdx.y * 256;
  const int n0 = blockIdx.x * 256;
  const int wm = (wave >> 2) * 128;
  const int wn = (wave & 3) * 64;
  const int lr = lane & 15;
  const int lq = lane >> 4;

  // ---- staging addresses: 2 A chunks + 2 B chunks per thread per K-tile ----
  const u16 *pA0, *pA1, *pB0, *pB1;
  int la0, la1, lb0, lb1;
  {
    auto mk = [&](int p, const u16* base, int nb) -> const u16* {
      int pr = p >> 3, cs = p & 7;
      int c  = cs ^ (pr & 7);
      int r  = pr * 2 + (c >> 2);    // logical row (row-paired layout)
      int kc = c & 3;                // 8-col chunk within BK=32
      return base + (size_t)(nb + r) * KP + kc * 8;
    };
    int p0 = tid, p1 = 512 + tid;
    pA0 = mk(p0, A, m0); pA1 = mk(p1, A, m0);
    pB0 = mk(p0, B, n0); pB1 = mk(p1, B, n0);
    la0 = p0 * 8;        la1 = p1 * 8;
    lb0 = 8192 + p0 * 8; lb1 = 8192 + p1 * 8;
  }

  // ---- fragment LDS offsets (u16 units within a slot) ----
  int aoff[8], boff[4];
  #pragma unroll
  for (int t = 0; t < 8; ++t) {
    int ra = wm + t * 16 + lr;
    int pr = ra >> 1, c = (ra & 1) * 4 + lq;
    aoff[t] = pr * 64 + ((c ^ (pr & 7)) * 8);
  }
  #pragma unroll
  for (int t = 0; t < 4; ++t) {
    int rb = wn + t * 16 + lr;
    int pr = rb >> 1, c = (rb & 1) * 4 + lq;
    boff[t] = 8192 + pr * 64 + ((c ^ (pr & 7)) * 8);
  }

  f32x4 acc[8][4] = {};

  // ---- prologue: stage K-tiles 0,1,2 into slots 0,1,2 ----
  #pragma unroll
  for (int s = 0; s < 3; ++s) {
    u16* sl = lds + (s << 14);
    gld_lds16(pA0, sl + la0); gld_lds16(pA1, sl + la1);
    gld_lds16(pB0, sl + lb0); gld_lds16(pB1, sl + lb1);
    pA0 += 32; pA1 += 32; pB0 += 32; pB1 += 32;
  }
  asm volatile("s_waitcnt vmcnt(8)" ::: "memory");   // K-tile 0 resident; 1,2 in flight
  __builtin_amdgcn_s_barrier();
  asm volatile("" ::: "memory");

  #pragma unroll 1
  for (int kt = 0; kt < NKT2; ++kt) {
    const u16* sA_ = lds + ((kt & 3) << 14);
    u16* stl = lds + (((kt + 3) & 3) << 14);
    const bool st = (kt < NKT2 - 3);
    if (st) {
      gld_lds16(pA0, stl + la0); gld_lds16(pA1, stl + la1);
      gld_lds16(pB0, stl + lb0); gld_lds16(pB1, stl + lb1);
      pA0 += 32; pA1 += 32; pB0 += 32; pB1 += 32;
    }
    bf16x8 af[8], bf[4];
    #pragma unroll
    for (int t = 0; t < 8; ++t) af[t] = *(const bf16x8*)&sA_[aoff[t]];
    #pragma unroll
    for (int t = 0; t < 4; ++t) bf[t] = *(const bf16x8*)&sA_[boff[t]];
    __builtin_amdgcn_s_setprio(1);
    #pragma unroll
    for (int ti = 0; ti < 8; ++ti)
      #pragma unroll
      for (int tj = 0; tj < 4; ++tj)
        acc[ti][tj] = __builtin_amdgcn_mfma_f32_16x16x32_bf16(af[ti], bf[tj], acc[ti][tj], 0, 0, 0);
    __builtin_amdgcn_s_setprio(0);
    if (st) asm volatile("s_waitcnt vmcnt(8)" ::: "memory");
    else    asm volatile("s_waitcnt vmcnt(0)" ::: "memory");
    __builtin_amdgcn_s_barrier();
    asm volatile("" ::: "memory");
  }

  // ---- epilogue.  C/D layout: col = lane&15, row = (lane>>4)*4 + reg ----
  const int sel = (blockIdx.x >= 24) ? 2 : (blockIdx.x >= 12 ? 1 : 0);

  float bv[4];
  #pragma unroll
  for (int tj = 0; tj < 4; ++tj) bv[tj] = bias[n0 + wn + tj * 16 + lr];
  #pragma unroll
  for (int ti = 0; ti < 8; ++ti)
    #pragma unroll
    for (int tj = 0; tj < 4; ++tj)
      #pragma unroll
      for (int rg = 0; rg < 4; ++rg)
        acc[ti][tj][rg] += bv[tj];

  if (sel == 2) {
    #pragma unroll
    for (int tj = 0; tj < 4; ++tj) {
      int n = n0 + wn + tj * 16 + lr;
      #pragma unroll
      for (int ti = 0; ti < 8; ++ti) {
        int mr = m0 + wm + ti * 16 + lq * 4;
        #pragma unroll
        for (int rg = 0; rg < 4; ++rg)
          out[(size_t)(mr + rg) * NDIM + n] = acc[ti][tj][rg];
      }
    }
    return;
  }

  // RMSNorm: per-row sum of squares over each head's 128 cols.
  float* ssq = (float*)lds;
  #pragma unroll
  for (int ti = 0; ti < 8; ++ti) {
    float pr4[4];
    #pragma unroll
    for (int rg = 0; rg < 4; ++rg) {
      float s = 0.f;
      #pragma unroll
      for (int tj = 0; tj < 4; ++tj) s += acc[ti][tj][rg] * acc[ti][tj][rg];
      pr4[rg] = s;
    }
    #pragma unroll
    for (int off = 1; off < 16; off <<= 1)
      #pragma unroll
      for (int rg = 0; rg < 4; ++rg) pr4[rg] += __shfl_xor(pr4[rg], off);
    #pragma unroll
    for (int rg = 0; rg < 4; ++rg)
      if (lr == (ti & 3) * 4 + rg)
        ssq[(wn >> 6) * 256 + wm + ti * 16 + lq * 4 + rg] = pr4[rg];
  }
  __syncthreads();

  const float* nrm = sel ? norm_k : norm_q;
  float gm[4];
  #pragma unroll
  for (int tj = 0; tj < 4; ++tj) gm[tj] = nrm[(wn & 64) + tj * 16 + lr];
  const float2* rot2 = (const float2*)rot;
  const float sgn = (lr & 1) ? 1.0f : -1.0f;
  const int hb = (wn >> 7) * 512;

  #pragma unroll
  for (int ti = 0; ti < 8; ++ti) {
    #pragma unroll
    for (int rg = 0; rg < 4; ++rg) {
      int row = wm + ti * 16 + lq * 4 + rg;
      float tot = ssq[hb + row] + ssq[hb + 256 + row];
      float rs = rsqrtf(tot * (1.0f / 128.0f) + 1e-6f);
      int m = m0 + row;
      #pragma unroll
      for (int tj = 0; tj < 4; ++tj) {
        int nl = (wn & 64) + tj * 16 + lr;          // head-local col
        float v = acc[ti][tj][rg] * rs * gm[tj];
        float p = __shfl_xor(v, 1);                 // rope partner (same row, col^1)
        float2 cs = rot2[(size_t)m * 64 + (nl >> 1)];
        out[(size_t)m * NDIM + n0 + wn + tj * 16 + lr] = v * cs.x + sgn * (p * cs.y);
      }
    }
  }
}

extern "C" void kernel_launch(void* const* d_in, const int* in_sizes, int n_in,
                              void* d_out, int out_size, void* d_ws, size_t ws_size,
                              hipStream_t stream) {
  const float* x         = (const float*)d_in[0];
  const u32*   qweight   = (const u32*)d_in[1];
  const float* wscales   = (const float*)d_in[2];
  const float* bias      = (const float*)d_in[3];
  const float* lora_down = (const float*)d_in[4];
  const float* lora_up   = (const float*)d_in[5];
  const float* smooth    = (const float*)d_in[6];
  const float* norm_q    = (const float*)d_in[7];
  const float* norm_k    = (const float*)d_in[8];
  const float* rot       = (const float*)d_in[9];
  float* out = (float*)d_out;

  u16* Aex = (u16*)d_ws;                               // 4096*3136 bf16
  u16* Bex = Aex + (size_t)MDIM * KP;                  // 9216*3136 bf16

  static bool attr_set = false;
  if (!attr_set) {
    hipFuncSetAttribute(reinterpret_cast<const void*>(k_gemm),
                        hipFuncAttributeMaxDynamicSharedMemorySize, 131072);
    attr_set = true;
  }

  k_wdq<<<WB + PB, 256, 0, stream>>>(qweight, wscales, lora_up, Bex);
  k_quant<<<QB2, 256, 0, stream>>>(x, lora_down, smooth, Aex);
  k_gemm<<<dim3(NDIM / 256, MDIM / 256), 512, 131072, stream>>>(Aex, Bex, bias, norm_q, norm_k, rot, out);
}

// Round 4
// 512.997 us; speedup vs baseline: 1.1562x; 1.0368x over previous
//
#include <hip/hip_runtime.h>
#include <cstdint>

#define MDIM 4096
#define NDIM 9216
#define KDIM 3072
#define KP   3136   // 3072 + 32 lora + 32 zero pad = 98 tiles of 32
#define NKT2 97     // GEMM covers 97 K-tiles of 32 (3104 cols); zero tail tile skipped

#define QROWS 4
#define QB2 1024           // quant blocks (4 rows each)
#define WB 13824           // weight-dequant blocks
#define PB 2304            // B-pad blocks (9216*64/256)

typedef unsigned int u32;
typedef unsigned short u16;
typedef float f32x4 __attribute__((ext_vector_type(4)));
typedef __bf16 bf16x8 __attribute__((ext_vector_type(8)));

__device__ __forceinline__ u16 f2bf(float f) {
  u32 u = __float_as_uint(f);
  u32 r = u + 0x7fffu + ((u >> 16) & 1u);   // round-to-nearest-even
  return (u16)(r >> 16);
}

__device__ __forceinline__ float frcp(float f) { return __builtin_amdgcn_rcpf(f); }

__device__ __forceinline__ void gld_lds16(const void* g, void* l) {
  __builtin_amdgcn_global_load_lds((__attribute__((address_space(1))) void*)g,
                                   (__attribute__((address_space(3))) void*)l,
                                   16, 0, 0);
}

// ---------------- kernel 1a: activation smooth+quant+lora_act, 4 rows/block ----------------
__global__ __launch_bounds__(256) void k_quant(const float* __restrict__ x,
                        const float* __restrict__ lora_down, const float* __restrict__ smooth,
                        u16* __restrict__ Aex) {
  __shared__ float xs_s[QROWS][KDIM];   // 48 KB
  __shared__ float part[64 * 32];       // 8 KB  [chunk][rank]
  const int tid = threadIdx.x;
  const int m0 = blockIdx.x * QROWS;
  const int sub = tid & 15;

  #pragma unroll
  for (int r = 0; r < QROWS; ++r) {
    const float* xr = x + (size_t)(m0 + r) * KDIM;
    u16* arow = Aex + (size_t)(m0 + r) * KP;
    #pragma unroll
    for (int p = 0; p < 3; ++p) {
      int g = p * 16 + (tid >> 4);
      int k0 = g * 64 + sub * 4;
      float4 xv = *(const float4*)(xr + k0);
      float4 sv = *(const float4*)(smooth + k0);
      float a0 = xv.x * frcp(sv.x), a1 = xv.y * frcp(sv.y);
      float a2 = xv.z * frcp(sv.z), a3 = xv.w * frcp(sv.w);
      xs_s[r][k0+0] = a0; xs_s[r][k0+1] = a1; xs_s[r][k0+2] = a2; xs_s[r][k0+3] = a3;
      float am = fmaxf(fmaxf(fabsf(a0), fabsf(a1)), fmaxf(fabsf(a2), fabsf(a3)));
      am = fmaxf(am, __shfl_xor(am, 8, 16));
      am = fmaxf(am, __shfl_xor(am, 4, 16));
      am = fmaxf(am, __shfl_xor(am, 2, 16));
      am = fmaxf(am, __shfl_xor(am, 1, 16));
      float asc = fmaxf(am * (1.0f / 7.0f), 1e-8f);
      float iasc = frcp(asc);
      float q0 = fminf(7.f, fmaxf(-8.f, rintf(a0 * iasc)));
      float q1 = fminf(7.f, fmaxf(-8.f, rintf(a1 * iasc)));
      float q2 = fminf(7.f, fmaxf(-8.f, rintf(a2 * iasc)));
      float q3 = fminf(7.f, fmaxf(-8.f, rintf(a3 * iasc)));
      float d0 = q0 * asc, d1 = q1 * asc, d2 = q2 * asc, d3 = q3 * asc;
      u32 lo = (u32)f2bf(d0) | ((u32)f2bf(d1) << 16);
      u32 hi = (u32)f2bf(d2) | ((u32)f2bf(d3) << 16);
      *(uint2*)(arow + k0) = make_uint2(lo, hi);
    }
    if (tid < 32) arow[3104 + tid] = 0;   // zero pad tail
  }
  __syncthreads();

  // lora_act[r_row][rk] = sum_k xs[r_row][k] * lora_down[k][rk]
  const int c  = tid >> 2;
  const int r8 = (tid & 3) * 8;
  float a[QROWS][8] = {};
  const float* lp = lora_down + (size_t)c * 32 + r8;   // advance 64*32 floats per i
  #pragma unroll 2
  for (int i = 0; i < 48; ++i) {
    float4 l0 = *(const float4*)(lp);
    float4 l1 = *(const float4*)(lp + 4);
    #pragma unroll
    for (int r = 0; r < QROWS; ++r) {
      float xv = xs_s[r][i * 64 + c];
      a[r][0] = fmaf(xv, l0.x, a[r][0]); a[r][1] = fmaf(xv, l0.y, a[r][1]);
      a[r][2] = fmaf(xv, l0.z, a[r][2]); a[r][3] = fmaf(xv, l0.w, a[r][3]);
      a[r][4] = fmaf(xv, l1.x, a[r][4]); a[r][5] = fmaf(xv, l1.y, a[r][5]);
      a[r][6] = fmaf(xv, l1.z, a[r][6]); a[r][7] = fmaf(xv, l1.w, a[r][7]);
    }
    lp += 64 * 32;
  }
  #pragma unroll 1
  for (int r = 0; r < QROWS; ++r) {
    __syncthreads();
    *(float4*)(&part[c * 32 + r8])     = make_float4(a[r][0], a[r][1], a[r][2], a[r][3]);
    *(float4*)(&part[c * 32 + r8 + 4]) = make_float4(a[r][4], a[r][5], a[r][6], a[r][7]);
    __syncthreads();
    if (tid < 32) {
      float s = 0.f;
      #pragma unroll 8
      for (int cc = 0; cc < 64; ++cc) s += part[cc * 32 + tid];
      Aex[(size_t)(m0 + r) * KP + 3072 + tid] = f2bf(s);   // LORA_SCALE = 1.0
    }
  }
}

// ---------------- kernel 1b: int4 weight dequant + B lora/pad columns ----------------
__global__ __launch_bounds__(256) void k_wdq(const u32* __restrict__ qw,
                        const float* __restrict__ wsc, const float* __restrict__ lora_up,
                        u16* __restrict__ Bex) {
  const int tid = threadIdx.x;
  int bid = blockIdx.x;

  if (bid >= WB) {
    int idx = (bid - WB) * 256 + tid;        // < 9216*64
    int n = idx >> 6, c = idx & 63;
    u16 v = 0;
    if (c < 32) v = f2bf(lora_up[n * 32 + c]);
    Bex[(size_t)n * KP + 3072 + c] = v;
    return;
  }
  // per-block layout detect: int8 stored as sign-extended int32 (f=1) vs raw bytes (f=0)
  __shared__ int s_viol;
  u32 probe = qw[tid];
  bool ok = (probe >> 8) == ((probe & 0x80u) ? 0xffffffu : 0u);
  if (tid == 0) s_viol = 0;
  __syncthreads();
  if (!ok) atomicOr(&s_viol, 1);
  __syncthreads();
  const int f = (s_viol == 0);

  int idx = bid * 256 + tid;   // < 9216*384
  int n = idx / 384;
  int j = idx - n * 384;
  int k0 = j * 8;
  u32 w;
  if (f) {
    uint4 q4 = ((const uint4*)qw)[idx];      // 4 sign-extended int32s, coalesced 16B
    w = (q4.x & 0xffu) | ((q4.y & 0xffu) << 8) | ((q4.z & 0xffu) << 16) | ((q4.w & 0xffu) << 24);
  } else {
    w = qw[idx];
  }
  float ws = wsc[(k0 >> 6) * NDIM + n];
  u32 ow[4];
  #pragma unroll
  for (int b = 0; b < 4; ++b) {
    int by = (int)((w >> (8 * b)) & 0xffu);
    int lo = (by << 28) >> 28;   // low nibble (k even)
    int hi = (by << 24) >> 28;   // high nibble (k odd)
    ow[b] = (u32)f2bf((float)lo * ws) | ((u32)f2bf((float)hi * ws) << 16);
  }
  *(uint4*)(Bex + (size_t)n * KP + k0) = make_uint4(ow[0], ow[1], ow[2], ow[3]);
}

// ---------------- kernel 2: 256x256 MFMA GEMM, rolling-fragment ring pipeline ----------------
// 512 threads = 8 waves (2M x 4N), wave tile 128x64 (acc 8x4 of 16x16).
// BK=32, 4-slot LDS ring (128 KB dynamic), stage distance 3.
// WAR-free DS/MFMA overlap: after MFMA group t (4 MFMAs reading af[t]) is issued,
// af[t] is immediately re-loaded from the NEXT slot (kt+1) — in-place roll, zero extra
// VGPRs; the 4 bf reads trail the cluster. sched_group_barrier pins the interleave
// (MFMA=0x8, DS_READ=0x100, VMEM_READ=0x20) so LLVM doesn't re-hoist the ds_reads.
// Counted-wait invariant (reads look ONE slot ahead): at barrier(kt) each wave has
// done vmcnt(4) -> its stages of iters <= kt-1 (slots <= kt+2) retired; barrier
// publishes across waves; iter kt+1 reads slot kt+2 mid-cluster -> resident. Prologue
// stages slots 0,1,2 and uses vmcnt(4) (slots 0,1 resident) before reading slot 0;
// iter 0's rolled reads hit slot 1 -> resident. Tail (kt>=94): vmcnt(0).
// WAR on LDS slots: stores of iter kt hit slot kt+3 == kt-1 (mod 4), whose reads
// completed before that iter's MFMAs (lgkm interlock) which precede barrier(kt-1).
__global__ __launch_bounds__(512) void k_gemm(const u16* __restrict__ A, const u16* __restrict__ B,
                                              const float* __restrict__ bias, const float* __restrict__ norm_q,
                                              const float* __restrict__ norm_k, const float* __restrict__ rot,
                                              float* __restrict__ out) {
  extern __shared__ u16 lds[];   // 4 slots * 16384 u16 = 128 KB
  const int tid  = threadIdx.x;
  const int lane = tid & 63;
  const int wave = tid >> 6;
  const int m0 = blockIdx.y * 256;
  const int n0 = blockIdx.x * 256;
  const int wm = (wave >> 2) * 128;
  const int wn = (wave & 3) * 64;
  const int lr = lane & 15;
  const int lq = lane >> 4;

  // ---- staging addresses: 2 A chunks + 2 B chunks per thread per K-tile ----
  const u16 *pA0, *pA1, *pB0, *pB1;
  int la0, la1, lb0, lb1;
  {
    auto mk = [&](int p, const u16* base, int nb) -> const u16* {
      int pr = p >> 3, cs = p & 7;
      int c  = cs ^ (pr & 7);
      int r  = pr * 2 + (c >> 2);    // logical row (row-paired layout)
      int kc = c & 3;                // 8-col chunk within BK=32
      return base + (size_t)(nb + r) * KP + kc * 8;
    };
    int p0 = tid, p1 = 512 + tid;
    pA0 = mk(p0, A, m0); pA1 = mk(p1, A, m0);
    pB0 = mk(p0, B, n0); pB1 = mk(p1, B, n0);
    la0 = p0 * 8;        la1 = p1 * 8;
    lb0 = 8192 + p0 * 8; lb1 = 8192 + p1 * 8;
  }

  // ---- fragment LDS offsets (u16 units within a slot) ----
  int aoff[8], boff[4];
  #pragma unroll
  for (int t = 0; t < 8; ++t) {
    int ra = wm + t * 16 + lr;
    int pr = ra >> 1, c = (ra & 1) * 4 + lq;
    aoff[t] = pr * 64 + ((c ^ (pr & 7)) * 8);
  }
  #pragma unroll
  for (int t = 0; t < 4; ++t) {
    int rb = wn + t * 16 + lr;
    int pr = rb >> 1, c = (rb & 1) * 4 + lq;
    boff[t] = 8192 + pr * 64 + ((c ^ (pr & 7)) * 8);
  }

  f32x4 acc[8][4] = {};

  // ---- prologue: stage K-tiles 0,1,2 into slots 0,1,2 ----
  #pragma unroll
  for (int s = 0; s < 3; ++s) {
    u16* sl = lds + (s << 14);
    gld_lds16(pA0, sl + la0); gld_lds16(pA1, sl + la1);
    gld_lds16(pB0, sl + lb0); gld_lds16(pB1, sl + lb1);
    pA0 += 32; pA1 += 32; pB0 += 32; pB1 += 32;
  }
  asm volatile("s_waitcnt vmcnt(4)" ::: "memory");   // slots 0,1 resident; 2 in flight
  __builtin_amdgcn_s_barrier();
  asm volatile("" ::: "memory");

  bf16x8 af[8], bf[4];
  #pragma unroll
  for (int t = 0; t < 8; ++t) af[t] = *(const bf16x8*)&lds[aoff[t]];
  #pragma unroll
  for (int t = 0; t < 4; ++t) bf[t] = *(const bf16x8*)&lds[boff[t]];

  #pragma unroll 1
  for (int kt = 0; kt < NKT2 - 1; ++kt) {
    u16* stl = lds + (((kt + 3) & 3) << 14);
    const u16* nsl = lds + (((kt + 1) & 3) << 14);
    if (kt < NKT2 - 3) {
      gld_lds16(pA0, stl + la0); gld_lds16(pA1, stl + la1);
      gld_lds16(pB0, stl + lb0); gld_lds16(pB1, stl + lb1);
      pA0 += 32; pA1 += 32; pB0 += 32; pB1 += 32;
    }
    __builtin_amdgcn_s_setprio(1);
    #pragma unroll
    for (int t = 0; t < 8; ++t) {
      #pragma unroll
      for (int tj = 0; tj < 4; ++tj)
        acc[t][tj] = __builtin_amdgcn_mfma_f32_16x16x32_bf16(af[t], bf[tj], acc[t][tj], 0, 0, 0);
      af[t] = *(const bf16x8*)&nsl[aoff[t]];   // roll: WAR only vs the 4 just-issued MFMAs
    }
    #pragma unroll
    for (int t = 0; t < 4; ++t) bf[t] = *(const bf16x8*)&nsl[boff[t]];
    __builtin_amdgcn_s_setprio(0);
    // pin the interleave: stage loads first, then 8 x {4 MFMA, 1 ds_read}, then 4 ds_read
    __builtin_amdgcn_sched_group_barrier(0x020, 4, 0);   // VMEM_READ (global_load_lds)
    #pragma unroll
    for (int g = 0; g < 8; ++g) {
      __builtin_amdgcn_sched_group_barrier(0x008, 4, 0); // MFMA
      __builtin_amdgcn_sched_group_barrier(0x100, 1, 0); // DS_READ
    }
    __builtin_amdgcn_sched_group_barrier(0x100, 4, 0);   // trailing bf reads
    if (kt < NKT2 - 3) asm volatile("s_waitcnt vmcnt(4)" ::: "memory");
    else               asm volatile("s_waitcnt vmcnt(0)" ::: "memory");
    __builtin_amdgcn_s_barrier();
    asm volatile("" ::: "memory");
  }
  // tail K-tile 96: MFMA only (frags loaded during iter 95)
  #pragma unroll
  for (int t = 0; t < 8; ++t)
    #pragma unroll
    for (int tj = 0; tj < 4; ++tj)
      acc[t][tj] = __builtin_amdgcn_mfma_f32_16x16x32_bf16(af[t], bf[tj], acc[t][tj], 0, 0, 0);

  // ---- epilogue.  C/D layout: col = lane&15, row = (lane>>4)*4 + reg ----
  const int sel = (blockIdx.x >= 24) ? 2 : (blockIdx.x >= 12 ? 1 : 0);

  float bv[4];
  #pragma unroll
  for (int tj = 0; tj < 4; ++tj) bv[tj] = bias[n0 + wn + tj * 16 + lr];
  #pragma unroll
  for (int ti = 0; ti < 8; ++ti)
    #pragma unroll
    for (int tj = 0; tj < 4; ++tj)
      #pragma unroll
      for (int rg = 0; rg < 4; ++rg)
        acc[ti][tj][rg] += bv[tj];

  if (sel == 2) {
    #pragma unroll
    for (int tj = 0; tj < 4; ++tj) {
      int n = n0 + wn + tj * 16 + lr;
      #pragma unroll
      for (int ti = 0; ti < 8; ++ti) {
        int mr = m0 + wm + ti * 16 + lq * 4;
        #pragma unroll
        for (int rg = 0; rg < 4; ++rg)
          out[(size_t)(mr + rg) * NDIM + n] = acc[ti][tj][rg];
      }
    }
    return;
  }

  // RMSNorm: per-row sum of squares over each head's 128 cols.
  __syncthreads();   // all waves' slot-96 reads done (lgkm before their MFMAs) -> safe to reuse LDS
  float* ssq = (float*)lds;
  #pragma unroll
  for (int ti = 0; ti < 8; ++ti) {
    float pr4[4];
    #pragma unroll
    for (int rg = 0; rg < 4; ++rg) {
      float s = 0.f;
      #pragma unroll
      for (int tj = 0; tj < 4; ++tj) s += acc[ti][tj][rg] * acc[ti][tj][rg];
      pr4[rg] = s;
    }
    #pragma unroll
    for (int off = 1; off < 16; off <<= 1)
      #pragma unroll
      for (int rg = 0; rg < 4; ++rg) pr4[rg] += __shfl_xor(pr4[rg], off);
    #pragma unroll
    for (int rg = 0; rg < 4; ++rg)
      if (lr == (ti & 3) * 4 + rg)
        ssq[(wn >> 6) * 256 + wm + ti * 16 + lq * 4 + rg] = pr4[rg];
  }
  __syncthreads();

  const float* nrm = sel ? norm_k : norm_q;
  float gm[4];
  #pragma unroll
  for (int tj = 0; tj < 4; ++tj) gm[tj] = nrm[(wn & 64) + tj * 16 + lr];
  const float2* rot2 = (const float2*)rot;
  const float sgn = (lr & 1) ? 1.0f : -1.0f;
  const int hb = (wn >> 7) * 512;

  #pragma unroll
  for (int ti = 0; ti < 8; ++ti) {
    #pragma unroll
    for (int rg = 0; rg < 4; ++rg) {
      int row = wm + ti * 16 + lq * 4 + rg;
      float tot = ssq[hb + row] + ssq[hb + 256 + row];
      float rs = rsqrtf(tot * (1.0f / 128.0f) + 1e-6f);
      int m = m0 + row;
      #pragma unroll
      for (int tj = 0; tj < 4; ++tj) {
        int nl = (wn & 64) + tj * 16 + lr;          // head-local col
        float v = acc[ti][tj][rg] * rs * gm[tj];
        float p = __shfl_xor(v, 1);                 // rope partner (same row, col^1)
        float2 cs = rot2[(size_t)m * 64 + (nl >> 1)];
        out[(size_t)m * NDIM + n0 + wn + tj * 16 + lr] = v * cs.x + sgn * (p * cs.y);
      }
    }
  }
}

extern "C" void kernel_launch(void* const* d_in, const int* in_sizes, int n_in,
                              void* d_out, int out_size, void* d_ws, size_t ws_size,
                              hipStream_t stream) {
  const float* x         = (const float*)d_in[0];
  const u32*   qweight   = (const u32*)d_in[1];
  const float* wscales   = (const float*)d_in[2];
  const float* bias      = (const float*)d_in[3];
  const float* lora_down = (const float*)d_in[4];
  const float* lora_up   = (const float*)d_in[5];
  const float* smooth    = (const float*)d_in[6];
  const float* norm_q    = (const float*)d_in[7];
  const float* norm_k    = (const float*)d_in[8];
  const float* rot       = (const float*)d_in[9];
  float* out = (float*)d_out;

  u16* Aex = (u16*)d_ws;                               // 4096*3136 bf16
  u16* Bex = Aex + (size_t)MDIM * KP;                  // 9216*3136 bf16

  static bool attr_set = false;
  if (!attr_set) {
    hipFuncSetAttribute(reinterpret_cast<const void*>(k_gemm),
                        hipFuncAttributeMaxDynamicSharedMemorySize, 131072);
    attr_set = true;
  }

  k_wdq<<<WB + PB, 256, 0, stream>>>(qweight, wscales, lora_up, Bex);
  k_quant<<<QB2, 256, 0, stream>>>(x, lora_down, smooth, Aex);
  k_gemm<<<dim3(NDIM / 256, MDIM / 256), 512, 131072, stream>>>(Aex, Bex, bias, norm_q, norm_k, rot, out);
}